// Round 11
// baseline (262.707 us; speedup 1.0000x reference)
//
#include <hip/hip_runtime.h>
#include <math.h>

#define NN 2
#define DD 16
#define HH 32
#define WW 32
#define DIN 18
#define HIN 34
#define WIN 34
#define NVOX 32768
#define NPAD (NN*DIN*HIN*WIN)    // 41616
#define PLANE (DIN*HIN*WIN)      // 20808
#define ROWS 432                 // 324 offset + 108 mask rows
#define SOMSTR 436               // s_om2 per-voxel stride in shorts

// ws float offsets (xpg has 16-float zero pads on both sides for clamped reads):
#define WS_XPG     16                        // bf16 value tensor [g][n][z][y][x][16ch]
#define XPG_FLOATS (NPAD*32)                 // 1,331,712 floats = NPAD*64 bf16
#define WS_DWT     (WS_XPG + XPG_FLOATS + 16)   // 1728 f32: dw_w transposed [k][c]
#define WS_CMBB    (WS_DWT + 1728)           // 27648 bf16: heads weights [r][c]
#define WS_OUTB    (WS_CMBB + 13824)         // 4096 bf16: out_w native [j][c]

// prep work item counts (striped across first blocks of prep_vp)
#define PREP_DWT   1728
#define PREP_CMB   27648
#define PREP_OUT   4096
#define PREP_PADS  32
#define PREP_TOTAL (PREP_DWT + PREP_CMB + PREP_OUT + PREP_PADS)   // 33504
#define PREP_BLOCKS 131                                           // 131*256 >= 33504
#define VP_BLOCKS  651                                            // ceil(NPAD/64)

typedef short  bf16x8 __attribute__((ext_vector_type(8)));
typedef float  f32x4  __attribute__((ext_vector_type(4)));

__device__ __forceinline__ unsigned short f2bf(float x) {
    unsigned u = __builtin_bit_cast(unsigned, x);
    u += 0x7fff + ((u >> 16) & 1);
    return (unsigned short)(u >> 16);
}
__device__ __forceinline__ float bf2f(unsigned short v) {
    return __builtin_bit_cast(float, ((unsigned)v) << 16);
}
__device__ __forceinline__ float bflo(unsigned u) {
    return __builtin_bit_cast(float, u << 16);
}
__device__ __forceinline__ float bfhi(unsigned u) {
    return __builtin_bit_cast(float, u & 0xffff0000u);
}
__device__ __forceinline__ bf16x8 pack8(float4 a, float4 b) {
    bf16x8 r;
    r[0] = (short)f2bf(a.x); r[1] = (short)f2bf(a.y);
    r[2] = (short)f2bf(a.z); r[3] = (short)f2bf(a.w);
    r[4] = (short)f2bf(b.x); r[5] = (short)f2bf(b.y);
    r[6] = (short)f2bf(b.z); r[7] = (short)f2bf(b.w);
    return r;
}

// ---------------------------------------------------------------------------
// Fused prep + value projection over the PADDED grid (border stores zeros).
// 651 blocks x 64 padded voxels; wave u owns voxels b*64+u*16 .. +15
// (round-10 bug fix: waves were all computing the same 16 voxels, 4x waste).
// ---------------------------------------------------------------------------
__global__ __launch_bounds__(256) void prep_vp(
        const float* __restrict__ inp,
        const float* __restrict__ in_w,  const float* __restrict__ out_w,
        const float* __restrict__ off_w, const float* __restrict__ mask_w,
        const float* __restrict__ dw_w,  const float* __restrict__ in_b,
        float* __restrict__ ws) {
    __shared__ __align__(16) unsigned short inB[4096];   // bf16 in_w [j][c]

    int t = threadIdx.x;
    int b = blockIdx.x;

    for (int i = t; i < 4096; i += 256) inB[i] = f2bf(in_w[i]);

    if (b < PREP_BLOCKS) {
        int idx = b * 256 + t;
        if (idx < PREP_DWT) {
            int k = idx >> 6, c = idx & 63;
            ws[WS_DWT + idx] = dw_w[c * 27 + k];
        } else if (idx < PREP_DWT + PREP_CMB) {
            int j = idx - PREP_DWT;
            ((unsigned short*)(ws + WS_CMBB))[j] =
                f2bf(j < 20736 ? off_w[j] : mask_w[j - 20736]);
        } else if (idx < PREP_DWT + PREP_CMB + PREP_OUT) {
            int j = idx - PREP_DWT - PREP_CMB;
            ((unsigned short*)(ws + WS_OUTB))[j] = f2bf(out_w[j]);
        } else if (idx < PREP_TOTAL) {
            int j = idx - PREP_DWT - PREP_CMB - PREP_OUT;
            if (j < 16) ws[j] = 0.f;                                // front pad
            else        ws[WS_XPG + XPG_FLOATS + (j - 16)] = 0.f;   // back pad
        }
    }
    __syncthreads();

    unsigned short* xpg = (unsigned short*)(ws + WS_XPG);
    int u = t >> 6, lane = t & 63;
    int nid = lane & 15, quad = lane >> 4;

    int pv = b * 64 + u * 16 + nid;
    bool in_range = pv < NPAD;
    int wp = pv % 34, hp = (pv / 34) % 34, dp = (pv / 1156) % 18, n = pv / 20808;
    bool interior = in_range &&
        (wp >= 1 && wp <= 32 && hp >= 1 && hp <= 32 && dp >= 1 && dp <= 16);

    bf16x8 b0 = {0,0,0,0,0,0,0,0}, b1 = {0,0,0,0,0,0,0,0};
    if (interior) {
        int vox = (((n * 16 + (dp - 1)) * 32 + (hp - 1)) * 32) + (wp - 1);
        const float* ip = inp + (size_t)vox * 64;
        b0 = pack8(*(const float4*)(ip + quad * 8),
                   *(const float4*)(ip + quad * 8 + 4));
        b1 = pack8(*(const float4*)(ip + quad * 8 + 32),
                   *(const float4*)(ip + quad * 8 + 36));
    }

    #pragma unroll
    for (int tt = 0; tt < 4; ++tt) {
        bf16x8 a0 = *(const bf16x8*)&inB[(16 * tt + nid) * 64 + quad * 8];
        bf16x8 a1 = *(const bf16x8*)&inB[(16 * tt + nid) * 64 + quad * 8 + 32];
        f32x4 acc = {0.f, 0.f, 0.f, 0.f};
        acc = __builtin_amdgcn_mfma_f32_16x16x32_bf16(a0, b0, acc, 0, 0, 0);
        acc = __builtin_amdgcn_mfma_f32_16x16x32_bf16(a1, b1, acc, 0, 0, 0);
        float bs0 = in_b[16 * tt + 4 * quad + 0];
        float bs1 = in_b[16 * tt + 4 * quad + 1];
        float bs2 = in_b[16 * tt + 4 * quad + 2];
        float bs3 = in_b[16 * tt + 4 * quad + 3];
        unsigned d0 = 0u, d1 = 0u;
        if (interior) {
            d0 = (unsigned)f2bf(acc[0] + bs0) | ((unsigned)f2bf(acc[1] + bs1) << 16);
            d1 = (unsigned)f2bf(acc[2] + bs2) | ((unsigned)f2bf(acc[3] + bs3) << 16);
        }
        if (in_range)
            *(uint2*)&xpg[((size_t)tt * NPAD + pv) * 16 + 4 * quad] = make_uint2(d0, d1);
    }
}

// ---------------------------------------------------------------------------
// Fused main, 16 voxels / block (4 waves).
// ---------------------------------------------------------------------------
__global__ __launch_bounds__(256, 6) void dcn_main(
        const float* __restrict__ inp,
        const float* __restrict__ dw_b,
        const float* __restrict__ ln_g,  const float* __restrict__ ln_b,
        const float* __restrict__ off_b, const float* __restrict__ mask_b,
        const float* __restrict__ ws_ro,
        const float* __restrict__ out_b,
        float* __restrict__ out) {
    const unsigned short* xpg  = (const unsigned short*)(ws_ro + WS_XPG);
    const float* dwT  = ws_ro + WS_DWT;
    const unsigned short* cmbB = (const unsigned short*)(ws_ro + WS_CMBB);
    const unsigned short* outB = (const unsigned short*)(ws_ro + WS_OUTB);

    __shared__ __align__(16) unsigned short s_a[16 * 64];   // x1 bf16 [vox][ch]
    __shared__ __align__(16) unsigned short s_om2[16 * SOMSTR]; // [vb][item][ox,oy,oz,mask]
    __shared__ __align__(16) unsigned short s_vb[16 * 64];  // sampled vals bf16

    int t = threadIdx.x;
    int u = t >> 6, lane = t & 63;
    int nid = lane & 15, quad = lane >> 4;
    int hw = blockIdx.x;
    int L = (hw & 7) * 256 + (hw >> 3);       // XCD-contiguous remap (2048 blocks)
    int vox0 = L * 16;
    int w0 = vox0 & 31;
    int h0 = (vox0 >> 5) & 31;
    int d0 = (vox0 >> 10) & 15;
    int n  = vox0 >> 14;

    // ---- S1: depthwise conv (w-register-reuse) + LN + GELU
    {
        int c = lane;
        float dwb = dw_b[c];
        float acc[4] = {dwb, dwb, dwb, dwb};
        int wbase = w0 + u * 4;
        #pragma unroll
        for (int kd = 0; kd < 3; ++kd) {
            int dz = d0 + kd - 1;
            if ((unsigned)dz >= DD) continue;
            #pragma unroll
            for (int kh = 0; kh < 3; ++kh) {
                int hy = h0 + kh - 1;
                if ((unsigned)hy >= HH) continue;
                const float* rowp = inp + ((((size_t)n * DD + dz) * HH + hy) * WW) * 64 + c;
                float cv[6];
                #pragma unroll
                for (int j = 0; j < 6; ++j) {
                    int wx = wbase - 1 + j;
                    cv[j] = ((unsigned)wx < WW) ? rowp[(size_t)wx * 64] : 0.f;
                }
                float wt0 = dwT[(kd * 9 + kh * 3 + 0) * 64 + c];
                float wt1 = dwT[(kd * 9 + kh * 3 + 1) * 64 + c];
                float wt2 = dwT[(kd * 9 + kh * 3 + 2) * 64 + c];
                #pragma unroll
                for (int i = 0; i < 4; ++i) {
                    acc[i] = fmaf(cv[i],     wt0, acc[i]);
                    acc[i] = fmaf(cv[i + 1], wt1, acc[i]);
                    acc[i] = fmaf(cv[i + 2], wt2, acc[i]);
                }
            }
        }
        #pragma unroll
        for (int i = 0; i < 4; ++i) {
            float a = acc[i];
            float s = a, ss = a * a;
            #pragma unroll
            for (int m = 1; m < 64; m <<= 1) {
                s  += __shfl_xor(s,  m, 64);
                ss += __shfl_xor(ss, m, 64);
            }
            float mu  = s * (1.f / 64.f);
            float var = ss * (1.f / 64.f) - mu * mu;
            float x1 = (a - mu) * rsqrtf(var + 1e-6f) * ln_g[c] + ln_b[c];
            x1 = 0.5f * x1 * (1.f + erff(x1 * 0.70710678118654752f));
            s_a[(u * 4 + i) * 64 + c] = f2bf(x1);
        }
    }
    __syncthreads();

    // ---- S2: heads (432 rows) via MFMA; store point-major into s_om2
    {
        bf16x8 a0 = *(const bf16x8*)&s_a[nid * 64 + quad * 8];
        bf16x8 a1 = *(const bf16x8*)&s_a[nid * 64 + quad * 8 + 32];
        for (int tl = u; tl < 27; tl += 4) {
            int r = tl * 16 + nid;
            bf16x8 b0 = *(const bf16x8*)&cmbB[r * 64 + quad * 8];
            bf16x8 b1 = *(const bf16x8*)&cmbB[r * 64 + quad * 8 + 32];
            f32x4 acc = {0.f, 0.f, 0.f, 0.f};
            acc = __builtin_amdgcn_mfma_f32_16x16x32_bf16(a0, b0, acc, 0, 0, 0);
            acc = __builtin_amdgcn_mfma_f32_16x16x32_bf16(a1, b1, acc, 0, 0, 0);
            float bias;
            int addr;
            if (r < 324) {
                bias = off_b[r];
                addr = (r / 3) * 4 + (r % 3);       // item = (g*27+p), axis
            } else {
                bias = mask_b[r - 324];
                addr = (r - 324) * 4 + 3;           // item*4 + 3
            }
            #pragma unroll
            for (int k = 0; k < 4; ++k)
                s_om2[(quad * 4 + k) * SOMSTR + addr] = f2bf(acc[k] + bias);
        }
    }
    __syncthreads();

    // ---- S3: softmax over 27 mask entries per (vox, group); quad each
    {
        int pair = t >> 2, l = t & 3;
        int vb = pair >> 2, g = pair & 3;
        unsigned short* m = &s_om2[vb * SOMSTR + g * 108];   // item stride 4, mask at +3
        float e[7];
        float mx = -1e30f;
        #pragma unroll
        for (int j = 0; j < 7; ++j) {
            int p = l + 4 * j;
            float v = (p < 27) ? bf2f(m[p * 4 + 3]) : -1e30f;
            e[j] = v;
            mx = fmaxf(mx, v);
        }
        mx = fmaxf(mx, __shfl_xor(mx, 1, 64));
        mx = fmaxf(mx, __shfl_xor(mx, 2, 64));
        float sm = 0.f;
        #pragma unroll
        for (int j = 0; j < 7; ++j) {
            int p = l + 4 * j;
            e[j] = (p < 27) ? expf(e[j] - mx) : 0.f;
            sm += e[j];
        }
        sm += __shfl_xor(sm, 1, 64);
        sm += __shfl_xor(sm, 2, 64);
        float inv = 1.f / sm;
        #pragma unroll
        for (int j = 0; j < 7; ++j) {
            int p = l + 4 * j;
            if (p < 27) m[p * 4 + 3] = f2bf(e[j] * inv);
        }
    }
    __syncthreads();

    // ---- S4: gather with quad-distributed setup.
    // Points processed in chunks of 4: lane q of each quad computes the
    // per-point setup (validity-masked weights + clamped row indices) for
    // point 4c+q; consumers fetch the 10 values via __shfl (no barrier, no
    // LDS round-trip — VALU stays interleaved with loads for latency hiding).
    {
        int vb = lane >> 2, q = lane & 3;
        int chalf = q & 1, xhalf = q >> 1;
        int qo = q * 8;
        int qbase = lane & 0x3C;             // quad base lane
        int wv = w0 + vb;
        const unsigned short* omb = &s_om2[vb * SOMSTR + u * 108];
        const unsigned short* xg = xpg + ((size_t)u * NPAD + (size_t)n * PLANE) * 16;
        float acc[8] = {0.f, 0.f, 0.f, 0.f, 0.f, 0.f, 0.f, 0.f};
        #pragma unroll
        for (int c = 0; c < 7; ++c) {
            // --- setup for own point pown = 4c+q (clamped read if >= 27;
            //     garbage values are never consumed: tail chunk uses j<3 only)
            int pown = 4 * c + q;
            int pc = pown < 27 ? pown : 26;
            uint2 om4 = *(const uint2*)&omb[pc * 4];
            float ox = bflo(om4.x), oy = bfhi(om4.x);
            float oz = bflo(om4.y), msk = bfhi(om4.y);
            int ix = pc / 9, r9 = pc - ix * 9, iy = r9 / 3, iz = r9 - iy * 3;
            float px = (float)(wv + ix) + ox;
            float py = (float)(h0 + iy) + oy;
            float pz = (float)(d0 + iz) + oz;
            float fx0 = floorf(px); int x0 = (int)fx0; float fx = px - fx0;
            float fy0 = floorf(py); int y0 = (int)fy0; float fy = py - fy0;
            float fz0 = floorf(pz); int z0 = (int)fz0; float fz = pz - fz0;
            float wx0 = ((unsigned)x0       < WIN) ? (1.f - fx) : 0.f;
            float wx1 = ((unsigned)(x0 + 1) < WIN) ? fx         : 0.f;
            float wy0 = ((unsigned)y0       < HIN) ? (1.f - fy) : 0.f;
            float wy1 = ((unsigned)(y0 + 1) < HIN) ? fy         : 0.f;
            float wz0 = ((unsigned)z0       < DIN) ? (1.f - fz) : 0.f;
            float wz1 = ((unsigned)(z0 + 1) < DIN) ? fz         : 0.f;
            wz0 *= msk; wz1 *= msk;
            int x0c = min(max(x0, -1), WIN - 1);
            int y0c = min(max(y0, 0), HIN - 1), y1c = min(max(y0 + 1, 0), HIN - 1);
            int z0c = min(max(z0, 0), DIN - 1), z1c = min(max(z0 + 1, 0), DIN - 1);
            int zb0 = z0c * (HIN * WIN), zb1 = z1c * (HIN * WIN);
            int yb0 = y0c * WIN,         yb1 = y1c * WIN;
            int sr00 = zb0 + yb0 + x0c, sr01 = zb0 + yb1 + x0c;
            int sr10 = zb1 + yb0 + x0c, sr11 = zb1 + yb1 + x0c;
            float sm00 = wz0 * wy0, sm01 = wz0 * wy1;
            float sm10 = wz1 * wy0, sm11 = wz1 * wy1;
            // --- consume the chunk's points (j < 3 in the tail chunk)
            #pragma unroll
            for (int j = 0; j < 4; ++j) {
                if (4 * c + j >= 27) break;          // wave-uniform
                int src = qbase + j;
                int a00 = __shfl(sr00, src, 64);
                int a01 = __shfl(sr01, src, 64);
                int a10 = __shfl(sr10, src, 64);
                int a11 = __shfl(sr11, src, 64);
                float b00 = __shfl(sm00, src, 64);
                float b01 = __shfl(sm01, src, 64);
                float b10 = __shfl(sm10, src, 64);
                float b11 = __shfl(sm11, src, 64);
                float x0w = __shfl(wx0, src, 64);
                float x1w = __shfl(wx1, src, 64);
                uint4 t00 = *(const uint4*)(xg + a00 * 16 + qo);
                uint4 t01 = *(const uint4*)(xg + a01 * 16 + qo);
                uint4 t10 = *(const uint4*)(xg + a10 * 16 + qo);
                uint4 t11 = *(const uint4*)(xg + a11 * 16 + qo);
                float wxq = xhalf ? x1w : x0w;
                float w00 = wxq * b00, w01 = wxq * b01;
                float w10 = wxq * b10, w11 = wxq * b11;
                #define ACC8(T, W) { float w_ = (W); \
                    acc[0] = fmaf(w_, bflo(T.x), acc[0]); acc[1] = fmaf(w_, bfhi(T.x), acc[1]); \
                    acc[2] = fmaf(w_, bflo(T.y), acc[2]); acc[3] = fmaf(w_, bfhi(T.y), acc[3]); \
                    acc[4] = fmaf(w_, bflo(T.z), acc[4]); acc[5] = fmaf(w_, bfhi(T.z), acc[5]); \
                    acc[6] = fmaf(w_, bflo(T.w), acc[6]); acc[7] = fmaf(w_, bfhi(T.w), acc[7]); }
                ACC8(t00, w00) ACC8(t01, w01) ACC8(t10, w10) ACC8(t11, w11)
                #undef ACC8
            }
        }
        // combine the two x-halves (lanes q and q^2)
        #pragma unroll
        for (int i = 0; i < 8; ++i) acc[i] += __shfl_xor(acc[i], 2, 64);
        if (q < 2) {
            unsigned d0 = (unsigned)f2bf(acc[0]) | ((unsigned)f2bf(acc[1]) << 16);
            unsigned d1 = (unsigned)f2bf(acc[2]) | ((unsigned)f2bf(acc[3]) << 16);
            unsigned d2 = (unsigned)f2bf(acc[4]) | ((unsigned)f2bf(acc[5]) << 16);
            unsigned d3 = (unsigned)f2bf(acc[6]) | ((unsigned)f2bf(acc[7]) << 16);
            *(uint4*)&s_vb[vb * 64 + u * 16 + chalf * 8] = make_uint4(d0, d1, d2, d3);
        }
    }
    __syncthreads();

    // ---- S5: output projection via MFMA; wave u -> out channels 16u..16u+15
    {
        bf16x8 a0 = *(const bf16x8*)&s_vb[nid * 64 + quad * 8];
        bf16x8 a1 = *(const bf16x8*)&s_vb[nid * 64 + quad * 8 + 32];
        bf16x8 b0 = *(const bf16x8*)&outB[(u * 16 + nid) * 64 + quad * 8];
        bf16x8 b1 = *(const bf16x8*)&outB[(u * 16 + nid) * 64 + quad * 8 + 32];
        f32x4 acc = {0.f, 0.f, 0.f, 0.f};
        acc = __builtin_amdgcn_mfma_f32_16x16x32_bf16(a0, b0, acc, 0, 0, 0);
        acc = __builtin_amdgcn_mfma_f32_16x16x32_bf16(a1, b1, acc, 0, 0, 0);
        float ob = out_b[u * 16 + nid];
        #pragma unroll
        for (int k = 0; k < 4; ++k)
            out[(size_t)(vox0 + quad * 4 + k) * 64 + u * 16 + nid] = acc[k] + ob;
    }
}

extern "C" void kernel_launch(void* const* d_in, const int* in_sizes, int n_in,
                              void* d_out, int out_size, void* d_ws, size_t ws_size,
                              hipStream_t stream) {
    const float* inp    = (const float*)d_in[0];
    const float* dw_w   = (const float*)d_in[1];
    const float* dw_b   = (const float*)d_in[2];
    const float* ln_g   = (const float*)d_in[3];
    const float* ln_b   = (const float*)d_in[4];
    const float* off_w  = (const float*)d_in[5];
    const float* off_b  = (const float*)d_in[6];
    const float* mask_w = (const float*)d_in[7];
    const float* mask_b = (const float*)d_in[8];
    const float* in_w   = (const float*)d_in[9];
    const float* in_b   = (const float*)d_in[10];
    const float* out_w  = (const float*)d_in[11];
    const float* out_b  = (const float*)d_in[12];

    float* ws = (float*)d_ws;

    prep_vp<<<VP_BLOCKS, 256, 0, stream>>>(inp, in_w, out_w, off_w, mask_w,
                                           dw_w, in_b, ws);
    dcn_main<<<NVOX / 16, 256, 0, stream>>>(inp, dw_b, ln_g, ln_b,
                                            off_b, mask_b, ws, out_b,
                                            (float*)d_out);
}

// Round 12
// 152.161 us; speedup vs baseline: 1.7265x; 1.7265x over previous
//
#include <hip/hip_runtime.h>
#include <math.h>

#define NN 2
#define DD 16
#define HH 32
#define WW 32
#define DIN 18
#define HIN 34
#define WIN 34
#define NVOX 32768
#define NPAD (NN*DIN*HIN*WIN)    // 41616
#define PLANE (DIN*HIN*WIN)      // 20808
#define ROWS 432                 // 324 offset + 108 mask rows
#define SOMSTR 436               // s_om2 per-voxel stride in shorts

// ws float offsets (xpg has 16-float zero pads on both sides for clamped reads):
#define WS_XPG     16                        // bf16 value tensor [g][n][z][y][x][16ch]
#define XPG_FLOATS (NPAD*32)                 // 1,331,712 floats = NPAD*64 bf16
#define WS_DWT     (WS_XPG + XPG_FLOATS + 16)   // 1728 f32: dw_w transposed [k][c]
#define WS_CMBB    (WS_DWT + 1728)           // 27648 bf16: heads weights [r][c]
#define WS_OUTB    (WS_CMBB + 13824)         // 4096 bf16: out_w native [j][c]

// prep work item counts (striped across first blocks of prep_vp)
#define PREP_DWT   1728
#define PREP_CMB   27648
#define PREP_OUT   4096
#define PREP_PADS  32
#define PREP_TOTAL (PREP_DWT + PREP_CMB + PREP_OUT + PREP_PADS)   // 33504
#define PREP_BLOCKS 131                                           // 131*256 >= 33504
#define VP_BLOCKS  651                                            // ceil(NPAD/64)

typedef short  bf16x8 __attribute__((ext_vector_type(8)));
typedef float  f32x4  __attribute__((ext_vector_type(4)));

__device__ __forceinline__ unsigned short f2bf(float x) {
    unsigned u = __builtin_bit_cast(unsigned, x);
    u += 0x7fff + ((u >> 16) & 1);
    return (unsigned short)(u >> 16);
}
__device__ __forceinline__ float bf2f(unsigned short v) {
    return __builtin_bit_cast(float, ((unsigned)v) << 16);
}
__device__ __forceinline__ float bflo(unsigned u) {
    return __builtin_bit_cast(float, u << 16);
}
__device__ __forceinline__ float bfhi(unsigned u) {
    return __builtin_bit_cast(float, u & 0xffff0000u);
}
__device__ __forceinline__ bf16x8 pack8(float4 a, float4 b) {
    bf16x8 r;
    r[0] = (short)f2bf(a.x); r[1] = (short)f2bf(a.y);
    r[2] = (short)f2bf(a.z); r[3] = (short)f2bf(a.w);
    r[4] = (short)f2bf(b.x); r[5] = (short)f2bf(b.y);
    r[6] = (short)f2bf(b.z); r[7] = (short)f2bf(b.w);
    return r;
}

// ---------------------------------------------------------------------------
// Fused prep + value projection over the PADDED grid (border stores zeros).
// 651 blocks x 64 padded voxels; wave u owns voxels b*64+u*16 .. +15.
// ---------------------------------------------------------------------------
__global__ __launch_bounds__(256) void prep_vp(
        const float* __restrict__ inp,
        const float* __restrict__ in_w,  const float* __restrict__ out_w,
        const float* __restrict__ off_w, const float* __restrict__ mask_w,
        const float* __restrict__ dw_w,  const float* __restrict__ in_b,
        float* __restrict__ ws) {
    __shared__ __align__(16) unsigned short inB[4096];   // bf16 in_w [j][c]

    int t = threadIdx.x;
    int b = blockIdx.x;

    for (int i = t; i < 4096; i += 256) inB[i] = f2bf(in_w[i]);

    if (b < PREP_BLOCKS) {
        int idx = b * 256 + t;
        if (idx < PREP_DWT) {
            int k = idx >> 6, c = idx & 63;
            ws[WS_DWT + idx] = dw_w[c * 27 + k];
        } else if (idx < PREP_DWT + PREP_CMB) {
            int j = idx - PREP_DWT;
            ((unsigned short*)(ws + WS_CMBB))[j] =
                f2bf(j < 20736 ? off_w[j] : mask_w[j - 20736]);
        } else if (idx < PREP_DWT + PREP_CMB + PREP_OUT) {
            int j = idx - PREP_DWT - PREP_CMB;
            ((unsigned short*)(ws + WS_OUTB))[j] = f2bf(out_w[j]);
        } else if (idx < PREP_TOTAL) {
            int j = idx - PREP_DWT - PREP_CMB - PREP_OUT;
            if (j < 16) ws[j] = 0.f;                                // front pad
            else        ws[WS_XPG + XPG_FLOATS + (j - 16)] = 0.f;   // back pad
        }
    }
    __syncthreads();

    unsigned short* xpg = (unsigned short*)(ws + WS_XPG);
    int u = t >> 6, lane = t & 63;
    int nid = lane & 15, quad = lane >> 4;

    int pv = b * 64 + u * 16 + nid;
    bool in_range = pv < NPAD;
    int wp = pv % 34, hp = (pv / 34) % 34, dp = (pv / 1156) % 18, n = pv / 20808;
    bool interior = in_range &&
        (wp >= 1 && wp <= 32 && hp >= 1 && hp <= 32 && dp >= 1 && dp <= 16);

    bf16x8 b0 = {0,0,0,0,0,0,0,0}, b1 = {0,0,0,0,0,0,0,0};
    if (interior) {
        int vox = (((n * 16 + (dp - 1)) * 32 + (hp - 1)) * 32) + (wp - 1);
        const float* ip = inp + (size_t)vox * 64;
        b0 = pack8(*(const float4*)(ip + quad * 8),
                   *(const float4*)(ip + quad * 8 + 4));
        b1 = pack8(*(const float4*)(ip + quad * 8 + 32),
                   *(const float4*)(ip + quad * 8 + 36));
    }

    #pragma unroll
    for (int tt = 0; tt < 4; ++tt) {
        bf16x8 a0 = *(const bf16x8*)&inB[(16 * tt + nid) * 64 + quad * 8];
        bf16x8 a1 = *(const bf16x8*)&inB[(16 * tt + nid) * 64 + quad * 8 + 32];
        f32x4 acc = {0.f, 0.f, 0.f, 0.f};
        acc = __builtin_amdgcn_mfma_f32_16x16x32_bf16(a0, b0, acc, 0, 0, 0);
        acc = __builtin_amdgcn_mfma_f32_16x16x32_bf16(a1, b1, acc, 0, 0, 0);
        float bs0 = in_b[16 * tt + 4 * quad + 0];
        float bs1 = in_b[16 * tt + 4 * quad + 1];
        float bs2 = in_b[16 * tt + 4 * quad + 2];
        float bs3 = in_b[16 * tt + 4 * quad + 3];
        unsigned d0 = 0u, d1 = 0u;
        if (interior) {
            d0 = (unsigned)f2bf(acc[0] + bs0) | ((unsigned)f2bf(acc[1] + bs1) << 16);
            d1 = (unsigned)f2bf(acc[2] + bs2) | ((unsigned)f2bf(acc[3] + bs3) << 16);
        }
        if (in_range)
            *(uint2*)&xpg[((size_t)tt * NPAD + pv) * 16 + 4 * quad] = make_uint2(d0, d1);
    }
}

// ---------------------------------------------------------------------------
// Fused main, 16 voxels / block (4 waves). S4 = round-10 per-lane setup
// (round-11's quad-shfl distribution caused scratch spills: 600 MB of
// FETCH+WRITE, 2.5x regression — reverted).
// ---------------------------------------------------------------------------
__global__ __launch_bounds__(256, 6) void dcn_main(
        const float* __restrict__ inp,
        const float* __restrict__ dw_b,
        const float* __restrict__ ln_g,  const float* __restrict__ ln_b,
        const float* __restrict__ off_b, const float* __restrict__ mask_b,
        const float* __restrict__ ws_ro,
        const float* __restrict__ out_b,
        float* __restrict__ out) {
    const unsigned short* xpg  = (const unsigned short*)(ws_ro + WS_XPG);
    const float* dwT  = ws_ro + WS_DWT;
    const unsigned short* cmbB = (const unsigned short*)(ws_ro + WS_CMBB);
    const unsigned short* outB = (const unsigned short*)(ws_ro + WS_OUTB);

    __shared__ __align__(16) unsigned short s_a[16 * 64];   // x1 bf16 [vox][ch]
    __shared__ __align__(16) unsigned short s_om2[16 * SOMSTR]; // [vb][item][ox,oy,oz,mask]
    __shared__ __align__(16) unsigned short s_vb[16 * 64];  // sampled vals bf16

    int t = threadIdx.x;
    int u = t >> 6, lane = t & 63;
    int nid = lane & 15, quad = lane >> 4;
    int hw = blockIdx.x;
    int L = (hw & 7) * 256 + (hw >> 3);       // XCD-contiguous remap (2048 blocks)
    int vox0 = L * 16;
    int w0 = vox0 & 31;
    int h0 = (vox0 >> 5) & 31;
    int d0 = (vox0 >> 10) & 15;
    int n  = vox0 >> 14;

    // ---- S1: depthwise conv (w-register-reuse) + LN + GELU
    {
        int c = lane;
        float dwb = dw_b[c];
        float acc[4] = {dwb, dwb, dwb, dwb};
        int wbase = w0 + u * 4;
        #pragma unroll
        for (int kd = 0; kd < 3; ++kd) {
            int dz = d0 + kd - 1;
            if ((unsigned)dz >= DD) continue;
            #pragma unroll
            for (int kh = 0; kh < 3; ++kh) {
                int hy = h0 + kh - 1;
                if ((unsigned)hy >= HH) continue;
                const float* rowp = inp + ((((size_t)n * DD + dz) * HH + hy) * WW) * 64 + c;
                float cv[6];
                #pragma unroll
                for (int j = 0; j < 6; ++j) {
                    int wx = wbase - 1 + j;
                    cv[j] = ((unsigned)wx < WW) ? rowp[(size_t)wx * 64] : 0.f;
                }
                float wt0 = dwT[(kd * 9 + kh * 3 + 0) * 64 + c];
                float wt1 = dwT[(kd * 9 + kh * 3 + 1) * 64 + c];
                float wt2 = dwT[(kd * 9 + kh * 3 + 2) * 64 + c];
                #pragma unroll
                for (int i = 0; i < 4; ++i) {
                    acc[i] = fmaf(cv[i],     wt0, acc[i]);
                    acc[i] = fmaf(cv[i + 1], wt1, acc[i]);
                    acc[i] = fmaf(cv[i + 2], wt2, acc[i]);
                }
            }
        }
        #pragma unroll
        for (int i = 0; i < 4; ++i) {
            float a = acc[i];
            float s = a, ss = a * a;
            #pragma unroll
            for (int m = 1; m < 64; m <<= 1) {
                s  += __shfl_xor(s,  m, 64);
                ss += __shfl_xor(ss, m, 64);
            }
            float mu  = s * (1.f / 64.f);
            float var = ss * (1.f / 64.f) - mu * mu;
            float x1 = (a - mu) * rsqrtf(var + 1e-6f) * ln_g[c] + ln_b[c];
            x1 = 0.5f * x1 * (1.f + erff(x1 * 0.70710678118654752f));
            s_a[(u * 4 + i) * 64 + c] = f2bf(x1);
        }
    }
    __syncthreads();

    // ---- S2: heads (432 rows) via MFMA; store point-major into s_om2
    {
        bf16x8 a0 = *(const bf16x8*)&s_a[nid * 64 + quad * 8];
        bf16x8 a1 = *(const bf16x8*)&s_a[nid * 64 + quad * 8 + 32];
        for (int tl = u; tl < 27; tl += 4) {
            int r = tl * 16 + nid;
            bf16x8 b0 = *(const bf16x8*)&cmbB[r * 64 + quad * 8];
            bf16x8 b1 = *(const bf16x8*)&cmbB[r * 64 + quad * 8 + 32];
            f32x4 acc = {0.f, 0.f, 0.f, 0.f};
            acc = __builtin_amdgcn_mfma_f32_16x16x32_bf16(a0, b0, acc, 0, 0, 0);
            acc = __builtin_amdgcn_mfma_f32_16x16x32_bf16(a1, b1, acc, 0, 0, 0);
            float bias;
            int addr;
            if (r < 324) {
                bias = off_b[r];
                addr = (r / 3) * 4 + (r % 3);       // item = (g*27+p), axis
            } else {
                bias = mask_b[r - 324];
                addr = (r - 324) * 4 + 3;           // item*4 + 3
            }
            #pragma unroll
            for (int k = 0; k < 4; ++k)
                s_om2[(quad * 4 + k) * SOMSTR + addr] = f2bf(acc[k] + bias);
        }
    }
    __syncthreads();

    // ---- S3: softmax over 27 mask entries per (vox, group); quad each
    {
        int pair = t >> 2, l = t & 3;
        int vb = pair >> 2, g = pair & 3;
        unsigned short* m = &s_om2[vb * SOMSTR + g * 108];   // item stride 4, mask at +3
        float e[7];
        float mx = -1e30f;
        #pragma unroll
        for (int j = 0; j < 7; ++j) {
            int p = l + 4 * j;
            float v = (p < 27) ? bf2f(m[p * 4 + 3]) : -1e30f;
            e[j] = v;
            mx = fmaxf(mx, v);
        }
        mx = fmaxf(mx, __shfl_xor(mx, 1, 64));
        mx = fmaxf(mx, __shfl_xor(mx, 2, 64));
        float sm = 0.f;
        #pragma unroll
        for (int j = 0; j < 7; ++j) {
            int p = l + 4 * j;
            e[j] = (p < 27) ? expf(e[j] - mx) : 0.f;
            sm += e[j];
        }
        sm += __shfl_xor(sm, 1, 64);
        sm += __shfl_xor(sm, 2, 64);
        float inv = 1.f / sm;
        #pragma unroll
        for (int j = 0; j < 7; ++j) {
            int p = l + 4 * j;
            if (p < 27) m[p * 4 + 3] = f2bf(e[j] * inv);
        }
    }
    __syncthreads();

    // ---- S4: gather; per-lane setup (round-10 version), validity-masked
    // weights, clamped indices for load-address safety only.
    {
        int vb = lane >> 2, q = lane & 3;
        int chalf = q & 1, xhalf = q >> 1;
        int qo = q * 8;
        int wv = w0 + vb;
        const unsigned short* omb = &s_om2[vb * SOMSTR + u * 108];
        const unsigned short* xg = xpg + ((size_t)u * NPAD + (size_t)n * PLANE) * 16;
        float acc[8] = {0.f, 0.f, 0.f, 0.f, 0.f, 0.f, 0.f, 0.f};
        int p = 0;
        #pragma unroll
        for (int ix = 0; ix < 3; ++ix)
        #pragma unroll
        for (int iy = 0; iy < 3; ++iy)
        #pragma unroll
        for (int iz = 0; iz < 3; ++iz, ++p) {
            uint2 om4 = *(const uint2*)&omb[p * 4];
            float ox = bflo(om4.x), oy = bfhi(om4.x);
            float oz = bflo(om4.y), msk = bfhi(om4.y);
            float px = (float)(wv + ix) + ox;
            float py = (float)(h0 + iy) + oy;
            float pz = (float)(d0 + iz) + oz;
            float fx0 = floorf(px); int x0 = (int)fx0; float fx = px - fx0;
            float fy0 = floorf(py); int y0 = (int)fy0; float fy = py - fy0;
            float fz0 = floorf(pz); int z0 = (int)fz0; float fz = pz - fz0;
            float wx0 = ((unsigned)x0       < WIN) ? (1.f - fx) : 0.f;
            float wx1 = ((unsigned)(x0 + 1) < WIN) ? fx         : 0.f;
            float wy0 = ((unsigned)y0       < HIN) ? (1.f - fy) : 0.f;
            float wy1 = ((unsigned)(y0 + 1) < HIN) ? fy         : 0.f;
            float wz0 = ((unsigned)z0       < DIN) ? (1.f - fz) : 0.f;
            float wz1 = ((unsigned)(z0 + 1) < DIN) ? fz         : 0.f;
            wz0 *= msk; wz1 *= msk;
            int x0c = min(max(x0, -1), WIN - 1);
            int y0c = min(max(y0, 0), HIN - 1), y1c = min(max(y0 + 1, 0), HIN - 1);
            int z0c = min(max(z0, 0), DIN - 1), z1c = min(max(z0 + 1, 0), DIN - 1);
            int zb0 = z0c * (HIN * WIN), zb1 = z1c * (HIN * WIN);
            int yb0 = y0c * WIN,         yb1 = y1c * WIN;
            int r00 = zb0 + yb0 + x0c;
            int r01 = zb0 + yb1 + x0c;
            int r10 = zb1 + yb0 + x0c;
            int r11 = zb1 + yb1 + x0c;
            uint4 t00 = *(const uint4*)(xg + r00 * 16 + qo);
            uint4 t01 = *(const uint4*)(xg + r01 * 16 + qo);
            uint4 t10 = *(const uint4*)(xg + r10 * 16 + qo);
            uint4 t11 = *(const uint4*)(xg + r11 * 16 + qo);
            float wxq = xhalf ? wx1 : wx0;
            float w00 = wxq * wz0 * wy0;
            float w01 = wxq * wz0 * wy1;
            float w10 = wxq * wz1 * wy0;
            float w11 = wxq * wz1 * wy1;
            #define ACC8(T, W) { float w_ = (W); \
                acc[0] = fmaf(w_, bflo(T.x), acc[0]); acc[1] = fmaf(w_, bfhi(T.x), acc[1]); \
                acc[2] = fmaf(w_, bflo(T.y), acc[2]); acc[3] = fmaf(w_, bfhi(T.y), acc[3]); \
                acc[4] = fmaf(w_, bflo(T.z), acc[4]); acc[5] = fmaf(w_, bfhi(T.z), acc[5]); \
                acc[6] = fmaf(w_, bflo(T.w), acc[6]); acc[7] = fmaf(w_, bfhi(T.w), acc[7]); }
            ACC8(t00, w00) ACC8(t01, w01) ACC8(t10, w10) ACC8(t11, w11)
            #undef ACC8
        }
        // combine the two x-halves (lanes q and q^2)
        #pragma unroll
        for (int i = 0; i < 8; ++i) acc[i] += __shfl_xor(acc[i], 2, 64);
        if (q < 2) {
            unsigned d0 = (unsigned)f2bf(acc[0]) | ((unsigned)f2bf(acc[1]) << 16);
            unsigned d1 = (unsigned)f2bf(acc[2]) | ((unsigned)f2bf(acc[3]) << 16);
            unsigned d2 = (unsigned)f2bf(acc[4]) | ((unsigned)f2bf(acc[5]) << 16);
            unsigned d3 = (unsigned)f2bf(acc[6]) | ((unsigned)f2bf(acc[7]) << 16);
            *(uint4*)&s_vb[vb * 64 + u * 16 + chalf * 8] = make_uint4(d0, d1, d2, d3);
        }
    }
    __syncthreads();

    // ---- S5: output projection via MFMA; wave u -> out channels 16u..16u+15
    {
        bf16x8 a0 = *(const bf16x8*)&s_vb[nid * 64 + quad * 8];
        bf16x8 a1 = *(const bf16x8*)&s_vb[nid * 64 + quad * 8 + 32];
        bf16x8 b0 = *(const bf16x8*)&outB[(u * 16 + nid) * 64 + quad * 8];
        bf16x8 b1 = *(const bf16x8*)&outB[(u * 16 + nid) * 64 + quad * 8 + 32];
        f32x4 acc = {0.f, 0.f, 0.f, 0.f};
        acc = __builtin_amdgcn_mfma_f32_16x16x32_bf16(a0, b0, acc, 0, 0, 0);
        acc = __builtin_amdgcn_mfma_f32_16x16x32_bf16(a1, b1, acc, 0, 0, 0);
        float ob = out_b[u * 16 + nid];
        #pragma unroll
        for (int k = 0; k < 4; ++k)
            out[(size_t)(vox0 + quad * 4 + k) * 64 + u * 16 + nid] = acc[k] + ob;
    }
}

extern "C" void kernel_launch(void* const* d_in, const int* in_sizes, int n_in,
                              void* d_out, int out_size, void* d_ws, size_t ws_size,
                              hipStream_t stream) {
    const float* inp    = (const float*)d_in[0];
    const float* dw_w   = (const float*)d_in[1];
    const float* dw_b   = (const float*)d_in[2];
    const float* ln_g   = (const float*)d_in[3];
    const float* ln_b   = (const float*)d_in[4];
    const float* off_w  = (const float*)d_in[5];
    const float* off_b  = (const float*)d_in[6];
    const float* mask_w = (const float*)d_in[7];
    const float* mask_b = (const float*)d_in[8];
    const float* in_w   = (const float*)d_in[9];
    const float* in_b   = (const float*)d_in[10];
    const float* out_w  = (const float*)d_in[11];
    const float* out_b  = (const float*)d_in[12];

    float* ws = (float*)d_ws;

    prep_vp<<<VP_BLOCKS, 256, 0, stream>>>(inp, in_w, out_w, off_w, mask_w,
                                           dw_w, in_b, ws);
    dcn_main<<<NVOX / 16, 256, 0, stream>>>(inp, dw_b, ln_g, ln_b,
                                            off_b, mask_b, ws, out_b,
                                            (float*)d_out);
}